// Round 3
// baseline (345.220 us; speedup 1.0000x reference)
//
#include <hip/hip_runtime.h>

#define NC 32
#define NVOX (96*96*96)
#define NPAIR (NVOX/2)
#define NB 384            // blocks per sample; 2*NB = 768 = exactly 3 blocks/CU at waves=3
#define TPB 256

// per-block workspace slot layout (floats)
#define WS_CE     0
#define WS_SP     32
#define WS_SPT    64
#define WS_SINKI  96
#define WS_SIB    100
#define WS_TGT    104
#define WS_HIST   128
#define SLOT_STRIDE 1152          // 128 + 1024
#define NSLOT     (2 * NB)        // 768
#define FINAL_OFF (NSLOT * SLOT_STRIDE)
// completion counter lives INSIDE slot 0's dead field range (108..127 unused by
// finalize); ws footprint stays well under the proven-safe size.
#define CTR_IDX   124
#define NCHUNK    8
#define BLK_PER_CH (NB / NCHUNK)  // 48
#define RED_BLK_X ((2 * SLOT_STRIDE + TPB - 1) / TPB)   // 9 (9*256 == 2304 exactly)
#define RED_NBLK  (RED_BLK_X * NCHUNK)                  // 72

__device__ __forceinline__ float wave_reduce(float v) {
    #pragma unroll
    for (int off = 32; off > 0; off >>= 1)
        v += __shfl_down(v, off, 64);
    return v;
}

// 2 voxels per thread via float2 loads: doubles bytes-in-flight per load slot
// (512B/wave-load) and halves loop overhead. e^x rows live in registers
// (eva/evb, all indexing static via full unroll). launch_bounds(256,3) gives a
// 170-VGPR budget so the compiler can hoist the whole load batch (no spill at
// the ~135 needed). 768 blocks = exactly 3 blocks/CU.
__global__ __launch_bounds__(TPB, 3) void voxel_kernel(
    const float* __restrict__ images,
    const int*   __restrict__ targets,
    const int*   __restrict__ masks,     // bools promoted to 4-byte on device
    float* __restrict__ ws,
    float* __restrict__ pred_out)
{
    const int slot = blockIdx.x;
    const int b    = slot & 1;          // interleave samples across XCDs
    const int blk  = slot >> 1;
    const int tid  = threadIdx.x;

    __shared__ float s_hist[NC * NC];
    __shared__ float s_spt[NC];
    __shared__ float s_mf[NC];
    __shared__ float s_red[45];         // ce, sp[32], sinkI[4], sib[4], tgt[4]

    for (int i = tid; i < NC * NC; i += TPB) s_hist[i] = 0.f;
    if (tid < 45) s_red[tid] = 0.f;
    if (tid < NC) {
        s_spt[tid] = 0.f;
        s_mf[tid]  = (masks[b * NC + tid] != 0) ? 1.f : 0.f;
    }
    // block 0 zeroes the final accumulator + in-slot counter (no memset dispatch)
    if (slot == 0) {
        float* wsf = ws + FINAL_OFF;
        for (int i = tid; i < 2 * SLOT_STRIDE; i += TPB) wsf[i] = 0.f;
        if (tid == 0) *(unsigned int*)(ws + CTR_IDX) = 0u;
    }
    __syncthreads();

    const float2* img2 = (const float2*)(images + (size_t)b * NC * NVOX);
    const int2*   tgt2 = (const int2*)(targets + (size_t)b * NVOX);
    float2*       pout2 = (float2*)(pred_out + (size_t)b * NVOX);
    float*        wsb  = ws + (size_t)slot * SLOT_STRIDE;

    float sp[NC];
    #pragma unroll
    for (int c = 0; c < NC; ++c) sp[c] = 0.f;
    float ce = 0.f;
    float sinkI[4] = {0.f, 0.f, 0.f, 0.f};
    float sibc[4]  = {0.f, 0.f, 0.f, 0.f};
    float tgtc[4]  = {0.f, 0.f, 0.f, 0.f};

    for (int vp = blk * TPB + tid; vp < NPAIR; vp += NB * TPB) {
        const int2 y2 = tgt2[vp];

        const bool validA = (y2.x != 255);
        const bool validB = (y2.y != 255);
        const int  ysA = validA ? y2.x : 0;
        const int  ysB = validB ? y2.y : 0;
        const float vwA = validA ? 1.f : 0.f;
        const float vwB = validB ? 1.f : 0.f;
        const int  pyA = (ysA >= 4) ? (ysA - 4) / 7 : -1;
        const int  pyB = (ysB >= 4) ? (ysB - 4) / 7 : -1;
        const int  pyiA = (pyA >= 0) ? pyA : 0;
        const int  pyiB = (pyB >= 0) ? pyB : 0;

        // single sweep over channels: float2 load -> exp -> register rows;
        // online sum + argmax; target-class numerators via select chains.
        float eva[NC], evb[NC];
        float sumA = 0.f, sumB = 0.f;
        float bestA = -3.4e38f, bestB = -3.4e38f;
        float pyvA = 0.f, pyvB = 0.f, ppvA = 0.f, ppvB = 0.f;
        int   predA = 4, predB = 4;
        #pragma unroll
        for (int c = 0; c < NC; ++c) {
            const float2 x2 = img2[(size_t)c * NPAIR + vp];
            const float ea = __expf(x2.x);
            const float eb = __expf(x2.y);
            eva[c] = ea;  evb[c] = eb;
            sumA += ea;   sumB += eb;
            pyvA = (c == ysA) ? ea : pyvA;
            pyvB = (c == ysB) ? eb : pyvB;
            if (c < 4) {                            // parents are classes 0..3
                ppvA = (c == pyiA) ? ea : ppvA;
                ppvB = (c == pyiB) ? eb : ppvB;
            }
            if (c >= 4) {                           // argmax over leaves
                const bool gA = (x2.x > bestA);
                bestA = gA ? x2.x : bestA;
                predA = gA ? c : predA;
                const bool gB = (x2.y > bestB);
                bestB = gB ? x2.y : bestB;
                predB = gB ? c : predB;
            }
        }
        const float rinvA = 1.f / sumA;
        const float rinvB = 1.f / sumB;
        float2 pw; pw.x = (float)predA; pw.y = (float)predB;
        pout2[vp] = pw;

        const int ppA = (predA - 4) / 7;            // parent of pred
        const int ppB = (predB - 4) / 7;
        // sink-of-pred's-parent value: static 4-way select over group heads
        const float eskA = (ppA == 0) ? eva[4] : (ppA == 1) ? eva[11]
                         : (ppA == 2) ? eva[18] : eva[25];
        const float eskB = (ppB == 0) ? evb[4] : (ppB == 1) ? evb[11]
                         : (ppB == 2) ? evb[18] : evb[25];

        const float pA  = pyvA * rinvA, pB  = pyvB * rinvB;
        const float qA  = ppvA * rinvA, qB  = ppvB * rinvB;
        const float skA = eskA * rinvA, skB = eskB * rinvB;

        // CE
        float termA = __logf(fminf(fmaxf(pA, 1e-7f), 1.f - 1e-7f)) * s_mf[ysA];
        if (pyA >= 0)
            termA += __logf(fminf(fmaxf(qA, 1e-7f), 1.f - 1e-7f)) * s_mf[pyiA];
        float termB = __logf(fminf(fmaxf(pB, 1e-7f), 1.f - 1e-7f)) * s_mf[ysB];
        if (pyB >= 0)
            termB += __logf(fminf(fmaxf(qB, 1e-7f), 1.f - 1e-7f)) * s_mf[pyiB];
        ce -= termA * vwA + termB * vwB;

        // dice intersection terms
        atomicAdd(&s_spt[ysA], pA * vwA);
        if (pyA >= 0) atomicAdd(&s_spt[pyiA], qA * vwA);
        atomicAdd(&s_spt[ysB], pB * vwB);
        if (pyB >= 0) atomicAdd(&s_spt[pyiB], qB * vwB);

        // joint histogram
        atomicAdd(&s_hist[predA * NC + ysA], vwA);
        atomicAdd(&s_hist[predB * NC + ysB], vwB);

        // sink accounting (static k indices)
        const bool pmA = (s_mf[predA] == 0.f);
        const bool pmB = (s_mf[predB] == 0.f);
        #pragma unroll
        for (int k = 0; k < 4; ++k) {
            const int sk = 4 + 7 * k;
            {
                const bool ysib = (pyA == k) && (ysA != sk);
                const bool msib = pmA && (ppA == k) && (predA != sk);
                const bool sib  = ysib || msib;
                if (sib && validA) sibc[k] += 1.f;
                if ((ppA == k) && !sib && validA) { tgtc[k] += 1.f; sinkI[k] += skA; }
            }
            {
                const bool ysib = (pyB == k) && (ysB != sk);
                const bool msib = pmB && (ppB == k) && (predB != sk);
                const bool sib  = ysib || msib;
                if (sib && validB) sibc[k] += 1.f;
                if ((ppB == k) && !sib && validB) { tgtc[k] += 1.f; sinkI[k] += skB; }
            }
        }

        // per-class prob sums straight from registers
        const float rwA = rinvA * vwA;
        const float rwB = rinvB * vwB;
        #pragma unroll
        for (int c = 0; c < NC; ++c)
            sp[c] = __builtin_fmaf(evb[c], rwB, __builtin_fmaf(eva[c], rwA, sp[c]));
    }

    // wave reduce -> 4 LDS atomics per value -> private slot stores
    const int lane = tid & 63;
    {
        float r = wave_reduce(ce);
        if (lane == 0) atomicAdd(&s_red[0], r);
    }
    #pragma unroll
    for (int c = 0; c < NC; ++c) {
        float r = wave_reduce(sp[c]);
        if (lane == 0) atomicAdd(&s_red[1 + c], r);
    }
    #pragma unroll
    for (int k = 0; k < 4; ++k) {
        float r = wave_reduce(sinkI[k]);
        if (lane == 0) atomicAdd(&s_red[33 + k], r);
        r = wave_reduce(sibc[k]);
        if (lane == 0) atomicAdd(&s_red[37 + k], r);
        r = wave_reduce(tgtc[k]);
        if (lane == 0) atomicAdd(&s_red[41 + k], r);
    }
    __syncthreads();

    // plain coalesced stores to this block's private slot — zero global atomics
    for (int i = tid; i < NC * NC; i += TPB) wsb[WS_HIST + i] = s_hist[i];
    if (tid == 0) wsb[WS_CE] = s_red[0];
    if (tid < NC) {
        wsb[WS_SP  + tid] = s_red[1 + tid];
        wsb[WS_SPT + tid] = s_spt[tid];
    }
    if (tid < 4) {
        wsb[WS_SINKI + tid] = s_red[33 + tid];
        wsb[WS_SIB   + tid] = s_red[37 + tid];
        wsb[WS_TGT   + tid] = s_red[41 + tid];
    }
}

// stage A (72 blocks): each block sums a 48-slot chunk for 256 values, one
// atomic each; the LAST block to finish (fence + counter) runs the finalize
// in-place. The sum loop reads the counter float (slot-0 val 124) into
// wsf[124], a dead field finalize never reads — harmless.
__global__ __launch_bounds__(TPB) void reduce_kernel(
    const float* __restrict__ ws,
    float* __restrict__ wsf,
    const int* __restrict__ masks,
    float* __restrict__ out,
    unsigned int* __restrict__ ctr)
{
    const int v = blockIdx.x * TPB + threadIdx.x;   // value id, 0..2303 (exact)
    {
        const int b    = v / SLOT_STRIDE;
        const int val  = v % SLOT_STRIDE;
        const int blk0 = blockIdx.y * BLK_PER_CH;
        const float* base = ws + (size_t)b * SLOT_STRIDE + val;
        float s = 0.f;
        #pragma unroll 8
        for (int i = 0; i < BLK_PER_CH; ++i)
            s += base[(size_t)(2 * (blk0 + i)) * SLOT_STRIDE];
        atomicAdd(&wsf[v], s);
    }

    // last-block-done handshake (release: fence before count; acquire: fence after)
    __shared__ unsigned int s_last;
    __threadfence();
    __syncthreads();
    if (threadIdx.x == 0) s_last = atomicAdd(ctr, 1u);
    __syncthreads();
    if (s_last != RED_NBLK - 1) return;
    __threadfence();

    // ---- finalize (single block; threads 0..63 -> sample 0, 64..127 -> sample 1)
    __shared__ float f_col[2][NC], f_row[2][NC], f_dice[2][NC], f_mf[2][NC];
    const int t  = threadIdx.x & 63;
    const int fb = threadIdx.x >> 6;                // 0..3, only fb<2 active
    const bool act = (fb < 2) && (t < NC);

    if (act) {
        const float* hist = wsf + (size_t)fb * SLOT_STRIDE + WS_HIST;
        float cs = 0.f, rs = 0.f;
        for (int j = 0; j < NC; ++j) {
            cs += hist[j * NC + t];
            rs += hist[t * NC + j];
        }
        f_col[fb][t] = cs;
        f_row[fb][t] = rs;
        f_mf[fb][t]  = (masks[fb * NC + t] != 0) ? 1.f : 0.f;
    }
    __syncthreads();

    if (act) {
        const float* wsb  = wsf + (size_t)fb * SLOT_STRIDE;
        const float* hist = wsb + WS_HIST;
        const int c = t;
        float ycnt, pcnt, tp;
        if (c < 4) {
            int idx[8];
            idx[0] = c;
            for (int j = 0; j < 7; ++j) idx[1 + j] = 4 + 7 * c + j;
            ycnt = f_col[fb][c]; pcnt = f_row[fb][c];
            for (int j = 0; j < 7; ++j) { ycnt += f_col[fb][idx[1 + j]]; pcnt += f_row[fb][idx[1 + j]]; }
            tp = 0.f;
            for (int a = 0; a < 8; ++a)
                for (int d = 0; d < 8; ++d)
                    tp += hist[idx[a] * NC + idx[d]];
        } else {
            ycnt = f_col[fb][c]; pcnt = f_row[fb][c];
            tp = hist[c * NC + c];
        }
        const float mf = f_mf[fb][c];
        out[6 + (fb * NC + c) * 3 + 0] = tp * mf;
        out[6 + (fb * NC + c) * 3 + 1] = (pcnt - tp) * mf;
        out[6 + (fb * NC + c) * 3 + 2] = (ycnt - tp) * mf;
        f_dice[fb][c] = (1.f - 2.f * wsb[WS_SPT + c] / (wsb[WS_SP + c] + ycnt + 1e-5f)) * mf;
    }
    __syncthreads();

    if (fb < 2 && t == 0) {
        const float* wsb = wsf + (size_t)fb * SLOT_STRIDE;
        float vw = 0.f, dsum = 0.f, msum = 0.f;
        for (int c = 0; c < NC; ++c) {
            vw   += f_col[fb][c];
            dsum += f_dice[fb][c];
            msum += f_mf[fb][c];
        }
        const float cel  = wsb[WS_CE] / fmaxf(vw, 1.f);
        const float dice = dsum / fmaxf(msum, 1.f);
        float cnt = 0.f, sd = 0.f;
        for (int k = 0; k < 4; ++k) {
            float fl = (wsb[WS_SIB + k] > 0.f) ? 1.f : 0.f;
            float d  = 1.f - (2.f * wsb[WS_SINKI + k] + 1e-5f) /
                             (wsb[WS_SP + 4 + 7 * k] + wsb[WS_TGT + k] + 1e-5f);
            cnt += fl;
            sd  += d * fl;
        }
        out[fb * 3 + 0] = cel;
        out[fb * 3 + 1] = dice;
        out[fb * 3 + 2] = (cnt > 0.f) ? 0.1f * (sd / fmaxf(cnt, 1.f)) : 0.f;
    }
}

extern "C" void kernel_launch(void* const* d_in, const int* in_sizes, int n_in,
                              void* d_out, int out_size, void* d_ws, size_t ws_size,
                              hipStream_t stream) {
    const float* images  = (const float*)d_in[0];
    const int*   targets = (const int*)d_in[1];
    const int*   masks   = (const int*)d_in[2];
    float* out = (float*)d_out;
    float* ws  = (float*)d_ws;
    float* wsf = ws + FINAL_OFF;

    // out layout: loss (2*3) | cm (2*32*3) | pred (2*96^3) as floats
    // (wsf + counter are zeroed by voxel_kernel block 0 — no memset dispatch)
    voxel_kernel<<<dim3(NSLOT), dim3(TPB), 0, stream>>>(
        images, targets, masks, ws, out + 6 + 2 * NC * 3);
    reduce_kernel<<<dim3(RED_BLK_X, NCHUNK), dim3(TPB), 0, stream>>>(
        ws, wsf, masks, out, (unsigned int*)(ws + CTR_IDX));
}

// Round 5
// 338.783 us; speedup vs baseline: 1.0190x; 1.0190x over previous
//
#include <hip/hip_runtime.h>

#define NC 32
#define NVOX (96*96*96)
#define NPAIR (NVOX/2)        // 442368
#define NB 256                // blocks per sample; 2*NB = 512 = exactly 2 blocks/CU
#define TPB 256
#define STRIDE (NB * TPB)     // 65536 pairs per grid step
// NPAIR = 6.75 * STRIDE: blocks 0..191 do 7 iters, 192..255 do 6 (block-uniform)
#define FULL_BLKS 192

// per-block workspace slot layout (floats)
#define WS_CE     0
#define WS_SP     32
#define WS_SPT    64
#define WS_SINKI  96
#define WS_SIB    100
#define WS_TGT    104
#define WS_HIST   128
#define SLOT_STRIDE 1152          // 128 + 1024
#define NSLOT     (2 * NB)        // 512
#define FINAL_OFF (NSLOT * SLOT_STRIDE)
#define CTR_IDX   124             // counter in slot 0's dead field range (108..127)
#define NCHUNK    8
#define BLK_PER_CH (NB / NCHUNK)  // 32
#define RED_BLK_X ((2 * SLOT_STRIDE + TPB - 1) / TPB)   // 9 (9*256 == 2304 exactly)
#define RED_NBLK  (RED_BLK_X * NCHUNK)                  // 72

__device__ __forceinline__ float wave_reduce(float v) {
    #pragma unroll
    for (int off = 32; off > 0; off >>= 1)
        v += __shfl_down(v, off, 64);
    return v;
}

// Register double-buffered streaming: iteration i+1's 32 float2 loads are
// issued BEFORE iteration i's compute, so ~16KB/wave stays in flight under the
// ~2000-cycle compute phase (prev versions serialized: ev[] was live until the
// last sp-FMA, blocking next loads entirely). launch_bounds(256,2) gives a
// 256-VGPR budget for cur[64]+nxt[64]+sp[32]+misc (~190 live, no spill).
__global__ __launch_bounds__(TPB, 2) void voxel_kernel(
    const float* __restrict__ images,
    const int*   __restrict__ targets,
    const int*   __restrict__ masks,     // bools promoted to 4-byte on device
    float* __restrict__ ws,
    float* __restrict__ pred_out)
{
    const int slot = blockIdx.x;
    const int b    = slot & 1;          // interleave samples across XCDs
    const int blk  = slot >> 1;
    const int tid  = threadIdx.x;

    __shared__ float s_hist[NC * NC];
    __shared__ float s_spt[NC];
    __shared__ float s_mf[NC];
    __shared__ float s_red[45];         // ce, sp[32], sinkI[4], sib[4], tgt[4]

    for (int i = tid; i < NC * NC; i += TPB) s_hist[i] = 0.f;
    if (tid < 45) s_red[tid] = 0.f;
    if (tid < NC) {
        s_spt[tid] = 0.f;
        s_mf[tid]  = (masks[b * NC + tid] != 0) ? 1.f : 0.f;
    }
    // block 0 zeroes the final accumulator + in-slot counter (no memset dispatch)
    if (slot == 0) {
        float* wsf = ws + FINAL_OFF;
        for (int i = tid; i < 2 * SLOT_STRIDE; i += TPB) wsf[i] = 0.f;
        if (tid == 0) *(unsigned int*)(ws + CTR_IDX) = 0u;
    }
    __syncthreads();

    const float2* img2 = (const float2*)(images + (size_t)b * NC * NVOX);
    const int2*   tgt2 = (const int2*)(targets + (size_t)b * NVOX);
    float2*       pout2 = (float2*)(pred_out + (size_t)b * NVOX);
    float*        wsb  = ws + (size_t)slot * SLOT_STRIDE;

    float sp[NC];
    #pragma unroll
    for (int c = 0; c < NC; ++c) sp[c] = 0.f;
    float ce = 0.f;
    float sinkI[4] = {0.f, 0.f, 0.f, 0.f};
    float sibc[4]  = {0.f, 0.f, 0.f, 0.f};
    float tgtc[4]  = {0.f, 0.f, 0.f, 0.f};

    const int iters = (blk < FULL_BLKS) ? 7 : 6;   // block-uniform, no divergence
    int vp = blk * TPB + tid;

    // prologue: load iteration 0
    float2 cur[NC];
    #pragma unroll
    for (int c = 0; c < NC; ++c) cur[c] = img2[(size_t)c * NPAIR + vp];
    int2 y2 = tgt2[vp];

    for (int it = 0; it < iters; ++it) {
        const bool more = (it + 1 < iters);        // uniform per block
        const int  vpn  = vp + STRIDE;

        // ---- prefetch next iteration (in flight during the compute below)
        float2 nxt[NC];
        int2   y2n;
        if (more) {
            #pragma unroll
            for (int c = 0; c < NC; ++c) nxt[c] = img2[(size_t)c * NPAIR + vpn];
            y2n = tgt2[vpn];
        }

        // ---- compute on cur (bit-identical math to the verified kernel)
        const bool validA = (y2.x != 255);
        const bool validB = (y2.y != 255);
        const int  ysA = validA ? y2.x : 0;
        const int  ysB = validB ? y2.y : 0;
        const float vwA = validA ? 1.f : 0.f;
        const float vwB = validB ? 1.f : 0.f;
        const int  pyA = (ysA >= 4) ? (ysA - 4) / 7 : -1;
        const int  pyB = (ysB >= 4) ? (ysB - 4) / 7 : -1;
        const int  pyiA = (pyA >= 0) ? pyA : 0;
        const int  pyiB = (pyB >= 0) ? pyB : 0;

        float eva[NC], evb[NC];
        float sumA = 0.f, sumB = 0.f;
        float bestA = -3.4e38f, bestB = -3.4e38f;
        float pyvA = 0.f, pyvB = 0.f, ppvA = 0.f, ppvB = 0.f;
        int   predA = 4, predB = 4;
        #pragma unroll
        for (int c = 0; c < NC; ++c) {
            const float xa = cur[c].x;
            const float xb = cur[c].y;
            const float ea = __expf(xa);
            const float eb = __expf(xb);
            eva[c] = ea;  evb[c] = eb;
            sumA += ea;   sumB += eb;
            pyvA = (c == ysA) ? ea : pyvA;
            pyvB = (c == ysB) ? eb : pyvB;
            if (c < 4) {                            // parents are classes 0..3
                ppvA = (c == pyiA) ? ea : ppvA;
                ppvB = (c == pyiB) ? eb : ppvB;
            }
            if (c >= 4) {                           // argmax over leaves
                const bool gA = (xa > bestA);
                bestA = gA ? xa : bestA;
                predA = gA ? c : predA;
                const bool gB = (xb > bestB);
                bestB = gB ? xb : bestB;
                predB = gB ? c : predB;
            }
        }
        const float rinvA = 1.f / sumA;
        const float rinvB = 1.f / sumB;
        float2 pw; pw.x = (float)predA; pw.y = (float)predB;
        pout2[vp] = pw;

        const int ppA = (predA - 4) / 7;            // parent of pred
        const int ppB = (predB - 4) / 7;
        const float eskA = (ppA == 0) ? eva[4] : (ppA == 1) ? eva[11]
                         : (ppA == 2) ? eva[18] : eva[25];
        const float eskB = (ppB == 0) ? evb[4] : (ppB == 1) ? evb[11]
                         : (ppB == 2) ? evb[18] : evb[25];

        const float pA  = pyvA * rinvA, pB  = pyvB * rinvB;
        const float qA  = ppvA * rinvA, qB  = ppvB * rinvB;
        const float skA = eskA * rinvA, skB = eskB * rinvB;

        // CE
        float termA = __logf(fminf(fmaxf(pA, 1e-7f), 1.f - 1e-7f)) * s_mf[ysA];
        if (pyA >= 0)
            termA += __logf(fminf(fmaxf(qA, 1e-7f), 1.f - 1e-7f)) * s_mf[pyiA];
        float termB = __logf(fminf(fmaxf(pB, 1e-7f), 1.f - 1e-7f)) * s_mf[ysB];
        if (pyB >= 0)
            termB += __logf(fminf(fmaxf(qB, 1e-7f), 1.f - 1e-7f)) * s_mf[pyiB];
        ce -= termA * vwA + termB * vwB;

        // dice intersection terms
        atomicAdd(&s_spt[ysA], pA * vwA);
        if (pyA >= 0) atomicAdd(&s_spt[pyiA], qA * vwA);
        atomicAdd(&s_spt[ysB], pB * vwB);
        if (pyB >= 0) atomicAdd(&s_spt[pyiB], qB * vwB);

        // joint histogram
        atomicAdd(&s_hist[predA * NC + ysA], vwA);
        atomicAdd(&s_hist[predB * NC + ysB], vwB);

        // sink accounting (static k indices)
        const bool pmA = (s_mf[predA] == 0.f);
        const bool pmB = (s_mf[predB] == 0.f);
        #pragma unroll
        for (int k = 0; k < 4; ++k) {
            const int sk = 4 + 7 * k;
            {
                const bool ysib = (pyA == k) && (ysA != sk);
                const bool msib = pmA && (ppA == k) && (predA != sk);
                const bool sib  = ysib || msib;
                if (sib && validA) sibc[k] += 1.f;
                if ((ppA == k) && !sib && validA) { tgtc[k] += 1.f; sinkI[k] += skA; }
            }
            {
                const bool ysib = (pyB == k) && (ysB != sk);
                const bool msib = pmB && (ppB == k) && (predB != sk);
                const bool sib  = ysib || msib;
                if (sib && validB) sibc[k] += 1.f;
                if ((ppB == k) && !sib && validB) { tgtc[k] += 1.f; sinkI[k] += skB; }
            }
        }

        // per-class prob sums
        const float rwA = rinvA * vwA;
        const float rwB = rinvB * vwB;
        #pragma unroll
        for (int c = 0; c < NC; ++c)
            sp[c] = __builtin_fmaf(evb[c], rwB, __builtin_fmaf(eva[c], rwA, sp[c]));

        // ---- rotate buffers
        if (more) {
            #pragma unroll
            for (int c = 0; c < NC; ++c) cur[c] = nxt[c];
            y2 = y2n;
            vp = vpn;
        }
    }

    // wave reduce -> 4 LDS atomics per value -> private slot stores
    const int lane = tid & 63;
    {
        float r = wave_reduce(ce);
        if (lane == 0) atomicAdd(&s_red[0], r);
    }
    #pragma unroll
    for (int c = 0; c < NC; ++c) {
        float r = wave_reduce(sp[c]);
        if (lane == 0) atomicAdd(&s_red[1 + c], r);
    }
    #pragma unroll
    for (int k = 0; k < 4; ++k) {
        float r = wave_reduce(sinkI[k]);
        if (lane == 0) atomicAdd(&s_red[33 + k], r);
        r = wave_reduce(sibc[k]);
        if (lane == 0) atomicAdd(&s_red[37 + k], r);
        r = wave_reduce(tgtc[k]);
        if (lane == 0) atomicAdd(&s_red[41 + k], r);
    }
    __syncthreads();

    // plain coalesced stores to this block's private slot — zero global atomics
    for (int i = tid; i < NC * NC; i += TPB) wsb[WS_HIST + i] = s_hist[i];
    if (tid == 0) wsb[WS_CE] = s_red[0];
    if (tid < NC) {
        wsb[WS_SP  + tid] = s_red[1 + tid];
        wsb[WS_SPT + tid] = s_spt[tid];
    }
    if (tid < 4) {
        wsb[WS_SINKI + tid] = s_red[33 + tid];
        wsb[WS_SIB   + tid] = s_red[37 + tid];
        wsb[WS_TGT   + tid] = s_red[41 + tid];
    }
}

// stage A (72 blocks): each block sums a 32-slot chunk for 256 values, one
// atomic each; the LAST block to finish (fence + counter) runs the finalize
// in-place. The sum loop reads the counter float (slot-0 val 124) into
// wsf[124], a dead field finalize never reads — harmless.
__global__ __launch_bounds__(TPB) void reduce_kernel(
    const float* __restrict__ ws,
    float* __restrict__ wsf,
    const int* __restrict__ masks,
    float* __restrict__ out,
    unsigned int* __restrict__ ctr)
{
    const int v = blockIdx.x * TPB + threadIdx.x;   // value id, 0..2303 (exact)
    {
        const int b    = v / SLOT_STRIDE;
        const int val  = v % SLOT_STRIDE;
        const int blk0 = blockIdx.y * BLK_PER_CH;
        const float* base = ws + (size_t)b * SLOT_STRIDE + val;
        float s = 0.f;
        #pragma unroll 8
        for (int i = 0; i < BLK_PER_CH; ++i)
            s += base[(size_t)(2 * (blk0 + i)) * SLOT_STRIDE];
        atomicAdd(&wsf[v], s);
    }

    // last-block-done handshake (release: fence before count; acquire: fence after)
    __shared__ unsigned int s_last;
    __threadfence();
    __syncthreads();
    if (threadIdx.x == 0) s_last = atomicAdd(ctr, 1u);
    __syncthreads();
    if (s_last != RED_NBLK - 1) return;
    __threadfence();

    // ---- finalize (single block; threads 0..63 -> sample 0, 64..127 -> sample 1)
    __shared__ float f_col[2][NC], f_row[2][NC], f_dice[2][NC], f_mf[2][NC];
    const int t  = threadIdx.x & 63;
    const int fb = threadIdx.x >> 6;                // 0..3, only fb<2 active
    const bool act = (fb < 2) && (t < NC);

    if (act) {
        const float* hist = wsf + (size_t)fb * SLOT_STRIDE + WS_HIST;
        float cs = 0.f, rs = 0.f;
        for (int j = 0; j < NC; ++j) {
            cs += hist[j * NC + t];
            rs += hist[t * NC + j];
        }
        f_col[fb][t] = cs;
        f_row[fb][t] = rs;
        f_mf[fb][t]  = (masks[fb * NC + t] != 0) ? 1.f : 0.f;
    }
    __syncthreads();

    if (act) {
        const float* wsb  = wsf + (size_t)fb * SLOT_STRIDE;
        const float* hist = wsb + WS_HIST;
        const int c = t;
        float ycnt, pcnt, tp;
        if (c < 4) {
            int idx[8];
            idx[0] = c;
            for (int j = 0; j < 7; ++j) idx[1 + j] = 4 + 7 * c + j;
            ycnt = f_col[fb][c]; pcnt = f_row[fb][c];
            for (int j = 0; j < 7; ++j) { ycnt += f_col[fb][idx[1 + j]]; pcnt += f_row[fb][idx[1 + j]]; }
            tp = 0.f;
            for (int a = 0; a < 8; ++a)
                for (int d = 0; d < 8; ++d)
                    tp += hist[idx[a] * NC + idx[d]];
        } else {
            ycnt = f_col[fb][c]; pcnt = f_row[fb][c];
            tp = hist[c * NC + c];
        }
        const float mf = f_mf[fb][c];
        out[6 + (fb * NC + c) * 3 + 0] = tp * mf;
        out[6 + (fb * NC + c) * 3 + 1] = (pcnt - tp) * mf;
        out[6 + (fb * NC + c) * 3 + 2] = (ycnt - tp) * mf;
        f_dice[fb][c] = (1.f - 2.f * wsb[WS_SPT + c] / (wsb[WS_SP + c] + ycnt + 1e-5f)) * mf;
    }
    __syncthreads();

    if (fb < 2 && t == 0) {
        const float* wsb = wsf + (size_t)fb * SLOT_STRIDE;
        float vw = 0.f, dsum = 0.f, msum = 0.f;
        for (int c = 0; c < NC; ++c) {
            vw   += f_col[fb][c];
            dsum += f_dice[fb][c];
            msum += f_mf[fb][c];
        }
        const float cel  = wsb[WS_CE] / fmaxf(vw, 1.f);
        const float dice = dsum / fmaxf(msum, 1.f);
        float cnt = 0.f, sd = 0.f;
        for (int k = 0; k < 4; ++k) {
            float fl = (wsb[WS_SIB + k] > 0.f) ? 1.f : 0.f;
            float d  = 1.f - (2.f * wsb[WS_SINKI + k] + 1e-5f) /
                             (wsb[WS_SP + 4 + 7 * k] + wsb[WS_TGT + k] + 1e-5f);
            cnt += fl;
            sd  += d * fl;
        }
        out[fb * 3 + 0] = cel;
        out[fb * 3 + 1] = dice;
        out[fb * 3 + 2] = (cnt > 0.f) ? 0.1f * (sd / fmaxf(cnt, 1.f)) : 0.f;
    }
}

extern "C" void kernel_launch(void* const* d_in, const int* in_sizes, int n_in,
                              void* d_out, int out_size, void* d_ws, size_t ws_size,
                              hipStream_t stream) {
    const float* images  = (const float*)d_in[0];
    const int*   targets = (const int*)d_in[1];
    const int*   masks   = (const int*)d_in[2];
    float* out = (float*)d_out;
    float* ws  = (float*)d_ws;
    float* wsf = ws + FINAL_OFF;

    // out layout: loss (2*3) | cm (2*32*3) | pred (2*96^3) as floats
    // (wsf + counter are zeroed by voxel_kernel block 0 — no memset dispatch)
    voxel_kernel<<<dim3(NSLOT), dim3(TPB), 0, stream>>>(
        images, targets, masks, ws, out + 6 + 2 * NC * 3);
    reduce_kernel<<<dim3(RED_BLK_X, NCHUNK), dim3(TPB), 0, stream>>>(
        ws, wsf, masks, out, (unsigned int*)(ws + CTR_IDX));
}